// Round 8
// baseline (88.478 us; speedup 1.0000x reference)
//
#include <hip/hip_runtime.h>

// Linear (kernelized) attention, N=8 L=S=8192 H=8 D=32, fp32.
// out = (Q'·(K'^T V)) / (Q'·Ksum + eps), Q'/K' = elu(x)+1.
// The /v_length and *v_length in the reference cancel exactly (2^13).

constexpr int N_ = 8, L_ = 8192, S_ = 8192, H_ = 8, D_ = 32;
constexpr int NH = N_ * H_;                  // 64 (n,h) pairs
constexpr int PART_STRIDE = D_ * D_ + D_;    // 1024 KV + 32 Ksum = 1056
constexpr int LCH = 256;                     // L-chunk per phase-2 block
constexpr float EPS_ = 1e-6f;
constexpr int HD = H_ * D_;                  // 256 floats = 1KB per (n,s) row

__device__ __forceinline__ float fmap(float x) {
    // elu(x)+1  (alpha=1): x>0 ? x+1 : exp(x)
    return x > 0.0f ? x + 1.0f : __expf(x);
}

// ---------------- phase 1: partial KV (D x D) + Ksum per (n,h,s-chunk) -----
// CONTIGUITY FIX: 512-thread block = 8 waves; wave w owns head w of batch n.
// All 8 waves sweep the same s-rows in lockstep, so the block consumes the
// full contiguous 1KB K-row + 1KB V-row (previous versions read one 128B
// head-slice per 1KB stride -> scattered 128B DRAM requests capped at
// ~1.2TB/s across rounds 1-7). Per-wave inner loop = round-5's half-wave
// 4(d)x8(v) blocking + 2-deep ring (VGPR 52, no spill), verbatim.
// No cross-wave reduction needed (waves own distinct heads) -> zero LDS.
template<int SPLIT>
__global__ __launch_bounds__(512, 4) void lin_attn_phase1(
        const float* __restrict__ Kg, const float* __restrict__ Vg,
        float* __restrict__ part) {
    constexpr int CS = S_ / SPLIT;    // rows per block
    const int blk = blockIdx.x;
    const int n  = blk / SPLIT;
    const int sc = blk % SPLIT;
    const int t = threadIdx.x;
    const int w = t >> 6;             // wave 0..7 = head
    const int j = t & 63;             // lane
    const int half = j >> 5;          // 0/1: which of the 2 rows this beat
    const int jj = j & 31;
    const int d0 = (jj & 7) << 2;     // K quad: d0..d0+3
    const int v0 = (jj >> 3) << 3;    // V oct:  v0..v0+7

    float acc[4][8];
    #pragma unroll
    for (int a = 0; a < 4; ++a)
        #pragma unroll
        for (int b = 0; b < 8; ++b) acc[a][b] = 0.0f;
    float kp[4] = {0.f, 0.f, 0.f, 0.f};

    const size_t base = (size_t)n * S_ * HD
                      + (size_t)(sc * CS + half) * HD + w * D_;
    const float* kr = Kg + base + d0;
    const float* vr = Vg + base + v0;
    constexpr int STRIDE = 2 * HD;    // 2 rows per beat

#define BEAT(kq, va, vb) do {                                                  \
        float kd[4];                                                           \
        kd[0] = fmap((kq).x); kd[1] = fmap((kq).y);                            \
        kd[2] = fmap((kq).z); kd[3] = fmap((kq).w);                            \
        kp[0] += kd[0]; kp[1] += kd[1]; kp[2] += kd[2]; kp[3] += kd[3];        \
        const float vs[8] = {(va).x, (va).y, (va).z, (va).w,                   \
                             (vb).x, (vb).y, (vb).z, (vb).w};                  \
        _Pragma("unroll")                                                      \
        for (int a = 0; a < 4; ++a)                                            \
            _Pragma("unroll")                                                  \
            for (int bb = 0; bb < 8; ++bb)                                     \
                acc[a][bb] += kd[a] * vs[bb];                                  \
    } while (0)

    // prologue: beats 0 and 1 in flight (2-deep: 6 loads/wave outstanding)
    float4 kqA = *reinterpret_cast<const float4*>(kr);
    float4 vaA = *reinterpret_cast<const float4*>(vr);
    float4 vbA = *reinterpret_cast<const float4*>(vr + 4);
    float4 kqB = *reinterpret_cast<const float4*>(kr + STRIDE);
    float4 vaB = *reinterpret_cast<const float4*>(vr + STRIDE);
    float4 vbB = *reinterpret_cast<const float4*>(vr + STRIDE + 4);
    kr += 2 * STRIDE; vr += 2 * STRIDE;

    #pragma unroll 1
    for (int b = 0; b < (CS / 2 - 2) / 2; ++b) {   // 2 beats per iter
        float4 kqn = *reinterpret_cast<const float4*>(kr);
        float4 van = *reinterpret_cast<const float4*>(vr);
        float4 vbn = *reinterpret_cast<const float4*>(vr + 4);
        BEAT(kqA, vaA, vbA);
        kqA = kqn; vaA = van; vbA = vbn;
        kqn = *reinterpret_cast<const float4*>(kr + STRIDE);
        van = *reinterpret_cast<const float4*>(vr + STRIDE);
        vbn = *reinterpret_cast<const float4*>(vr + STRIDE + 4);
        BEAT(kqB, vaB, vbB);
        kqB = kqn; vaB = van; vbB = vbn;
        kr += 2 * STRIDE; vr += 2 * STRIDE;
    }
    BEAT(kqA, vaA, vbA);
    BEAT(kqB, vaB, vbB);
#undef BEAT

    // ---- cross-half (rows split even/odd) reduce, in-register ----
    #pragma unroll
    for (int a = 0; a < 4; ++a)
        #pragma unroll
        for (int bb = 0; bb < 8; ++bb)
            acc[a][bb] += __shfl_xor(acc[a][bb], 32);
    #pragma unroll
    for (int a = 0; a < 4; ++a) kp[a] += __shfl_xor(kp[a], 32);

    // ---- direct write: this wave owns head w exclusively ----
    if (j < 32) {
        float* P = part + ((size_t)sc * NH + n * H_ + w) * PART_STRIDE;
        #pragma unroll
        for (int a = 0; a < 4; ++a) {
            *reinterpret_cast<float4*>(&P[(d0 + a) * D_ + v0]) =
                make_float4(acc[a][0], acc[a][1], acc[a][2], acc[a][3]);
            *reinterpret_cast<float4*>(&P[(d0 + a) * D_ + v0 + 4]) =
                make_float4(acc[a][4], acc[a][5], acc[a][6], acc[a][7]);
        }
        if (j < 8)   // kp duplicated across v-groups; one writer per d-quad
            *reinterpret_cast<float4*>(&P[D_ * D_ + (j << 2)]) =
                make_float4(kp[0], kp[1], kp[2], kp[3]);
    }
}

// ---------------- reduce the SPLIT partials -------------------------------
template<int SPLIT>
__global__ __launch_bounds__(256) void lin_attn_reduce(
        const float* __restrict__ part, float* __restrict__ red) {
    const int i = blockIdx.x * 256 + threadIdx.x;
    if (i >= NH * PART_STRIDE) return;
    float s = 0.0f;
    #pragma unroll 8
    for (int sc = 0; sc < SPLIT; ++sc)
        s += part[(size_t)sc * (NH * PART_STRIDE) + i];
    red[i] = s;
}

// ---------------- phase 2: out = (Q'.KV) * zinv, zinv = 1/(Q'.Ksum+eps) ----
// (round-7 version verbatim)
__global__ __launch_bounds__(256) void lin_attn_phase2(
        const float* __restrict__ Qg, const float* __restrict__ red,
        float* __restrict__ outg) {
    constexpr int QTS = 32;           // Q tile rows
    constexpr int NLC = L_ / LCH;     // 32
    const int nh  = blockIdx.x / NLC;
    const int lcb = blockIdx.x % NLC;
    const int n = nh / H_, h = nh % H_;
    const int t = threadIdx.x;
    const int v  = t & 31;
    const int rb = t >> 5;            // 0..7
    const int r  = t >> 3;            // staging row 0..31
    const int c  = (t & 7) << 2;      // staging col

    __shared__ __align__(16) float Qt[QTS][D_];
    __shared__ float zinv_sh[QTS];

    // Pin this thread's KV column in registers (static indexing only).
    float kv[D_];
    const float* W = red + (size_t)nh * PART_STRIDE;
    #pragma unroll
    for (int d = 0; d < D_; ++d) kv[d] = W[d * D_ + v];
    // Ksum quad matching this thread's staging columns (runtime c -> load
    // from global, NOT a runtime-indexed register array).
    const float4 ksq = *reinterpret_cast<const float4*>(W + D_ * D_ + c);

    const size_t base = (size_t)n * L_ * H_ * D_ + (size_t)h * D_;
    const int l0 = lcb * LCH;
    for (int step = 0; step < LCH; step += QTS) {
        const float4 q4 = *reinterpret_cast<const float4*>(
            Qg + base + (size_t)(l0 + step + r) * (H_ * D_) + c);
        __syncthreads();   // previous Qt/zinv fully consumed
        float4 qf;
        qf.x = fmap(q4.x); qf.y = fmap(q4.y);
        qf.z = fmap(q4.z); qf.w = fmap(q4.w);
        *reinterpret_cast<float4*>(&Qt[r][c]) = qf;
        // per-row z: dot(q-quad, ksum-quad), folded across the 8 staging lanes
        float zp = qf.x * ksq.x + qf.y * ksq.y + qf.z * ksq.z + qf.w * ksq.w;
        zp += __shfl_xor(zp, 1);
        zp += __shfl_xor(zp, 2);
        zp += __shfl_xor(zp, 4);
        if ((t & 7) == 0) zinv_sh[r] = 1.0f / (zp + EPS_);
        __syncthreads();
        #pragma unroll
        for (int rr = 0; rr < 4; ++rr) {
            const int row = (rr << 3) + rb;
            float acc = 0.0f;
            #pragma unroll
            for (int d2 = 0; d2 < 16; ++d2) {   // b64 2-addr broadcast reads
                const float2 q = *reinterpret_cast<const float2*>(&Qt[row][d2 << 1]);
                acc += q.x * kv[(d2 << 1)] + q.y * kv[(d2 << 1) + 1];
            }
            outg[base + (size_t)(l0 + step + row) * (H_ * D_) + v] =
                acc * zinv_sh[row];
        }
    }
}

extern "C" void kernel_launch(void* const* d_in, const int* in_sizes, int n_in,
                              void* d_out, int out_size, void* d_ws, size_t ws_size,
                              hipStream_t stream) {
    const float* Q = (const float*)d_in[0];
    const float* K = (const float*)d_in[1];
    const float* V = (const float*)d_in[2];
    float* out  = (float*)d_out;
    float* part = (float*)d_ws;

    // Prefer SPLIT=64 (grid 512 = 2 blocks/CU, part = 17.3MB) if ws allows;
    // fall back to SPLIT=32 (proven footprint from earlier rounds).
    const size_t need64 = ((size_t)64 + 1) * NH * PART_STRIDE * sizeof(float);
    if (ws_size >= need64) {
        constexpr int SP = 64;
        float* red = part + (size_t)SP * NH * PART_STRIDE;
        lin_attn_phase1<SP><<<N_ * SP, 512, 0, stream>>>(K, V, part);
        lin_attn_reduce<SP><<<(NH * PART_STRIDE + 255) / 256, 256, 0, stream>>>(part, red);
        lin_attn_phase2<<<NH * (L_ / LCH), 256, 0, stream>>>(Q, red, out);
    } else {
        constexpr int SP = 32;
        float* red = part + (size_t)SP * NH * PART_STRIDE;
        lin_attn_phase1<SP><<<N_ * SP, 512, 0, stream>>>(K, V, part);
        lin_attn_reduce<SP><<<(NH * PART_STRIDE + 255) / 256, 256, 0, stream>>>(part, red);
        lin_attn_phase2<<<NH * (L_ / LCH), 256, 0, stream>>>(Q, red, out);
    }
}

// Round 9
// 79.765 us; speedup vs baseline: 1.1092x; 1.1092x over previous
//
#include <hip/hip_runtime.h>

// Linear (kernelized) attention, N=8 L=S=8192 H=8 D=32, fp32.
// out = (Q'·(K'^T V)) / (Q'·Ksum + eps), Q'/K' = elu(x)+1.
// The /v_length and *v_length in the reference cancel exactly (2^13).

constexpr int N_ = 8, L_ = 8192, S_ = 8192, H_ = 8, D_ = 32;
constexpr int NH = N_ * H_;                  // 64 (n,h) pairs
constexpr int PART_STRIDE = D_ * D_ + D_;    // 1024 KV + 32 Ksum = 1056
constexpr int LCH = 256;                     // L-chunk per phase-2 block
constexpr float EPS_ = 1e-6f;
constexpr int HD = H_ * D_;                  // 256 floats = 1KB per (n,s) row
constexpr int CHUNK = 32;                    // rows per DMA round: 32KB K + 32KB V

__device__ __forceinline__ float fmap(float x) {
    // elu(x)+1  (alpha=1): x>0 ? x+1 : exp(x)
    return x > 0.0f ? x + 1.0f : __expf(x);
}

// async global->LDS, 16B per lane. LDS dest is wave-uniform base + lane*16;
// global src is per-lane. (cdna_hip_programming.md §5, measured m97.)
__device__ __forceinline__ void dma16(const float* g, float* l) {
    __builtin_amdgcn_global_load_lds(
        (const __attribute__((address_space(1))) unsigned int*)g,
        (__attribute__((address_space(3))) unsigned int*)l, 16, 0, 0);
}

// ---------------- phase 1: partial KV (D x D) + Ksum per (n,chunk-col) -----
// Copy-identical load path: each DMA instr moves a contiguous 1KB with every
// lane on a DISTINCT float4 (rounds 1-8 all used lane-duplicated / 128B-
// granular loads and pinned at ~1.2TB/s). Staging is DMA (no VGPR ring ->
// no spill risk); 64KB LDS = 2 blocks/CU so one block's DMA drain overlaps
// the other block's compute. fmap applied once per element, in LDS, with
// conflict-free column-per-thread access; Ksum falls out as one register.
template<int SPL>
__global__ __launch_bounds__(256, 2) void lin_attn_phase1(
        const float* __restrict__ Kg, const float* __restrict__ Vg,
        float* __restrict__ part) {
    constexpr int CS_BLK = S_ / SPL;         // rows per block (128 @ SPL=64)
    constexpr int ROUNDS = CS_BLK / CHUNK;   // DMA rounds (4 @ SPL=64)
    const int blk = blockIdx.x;
    const int n = blk / SPL, c = blk % SPL;
    const int t = threadIdx.x;
    const int w = t >> 6;             // wave 0..3
    const int lane = t & 63;

    __shared__ __align__(16) float Kt[CHUNK][HD];   // 32KB
    __shared__ __align__(16) float Vt[CHUNK][HD];   // 32KB

    // consume roles: 8 head-groups x 32 threads; thread owns 8(d) x 4(v)
    const int hg = t >> 5;            // head 0..7
    const int i  = t & 31;
    const int d0 = (i >> 3) << 3;     // 0,8,16,24
    const int v0 = (i & 7) << 2;      // 0,4,...,28
    const int hcol = hg * D_;

    float acc[8][4];
    #pragma unroll
    for (int a = 0; a < 8; ++a)
        #pragma unroll
        for (int b = 0; b < 4; ++b) acc[a][b] = 0.0f;
    float kp = 0.0f;                  // Ksum for column t (fmap pass owns col t)

    const float* Kbase = Kg + (size_t)n * S_ * HD + (size_t)c * CS_BLK * HD;
    const float* Vbase = Vg + (size_t)n * S_ * HD + (size_t)c * CS_BLK * HD;
    float* Kf = &Kt[0][0];

    for (int r = 0; r < ROUNDS; ++r) {
        const float* ksrc = Kbase + (size_t)r * CHUNK * HD;
        const float* vsrc = Vbase + (size_t)r * CHUNK * HD;
        // stage 32KB K + 32KB V: per wave 8+8 DMA instrs, each a contiguous
        // 1KB with unique per-lane addresses (copy-kernel pattern).
        #pragma unroll
        for (int q = 0; q < 8; ++q) {
            const int off = (w * 8 + q) * 256;      // floats
            dma16(ksrc + off + lane * 4, &Kt[0][0] + off);
            dma16(vsrc + off + lane * 4, &Vt[0][0] + off);
        }
        __syncthreads();   // drains vmcnt(0): DMA complete

        // fmap K in place; thread t owns COLUMN t (idx = t + 256k -> col t,
        // row k): stride-1 lane access = conflict-free; kp = col-t Ksum.
        #pragma unroll 8
        for (int k = 0; k < CHUNK; ++k) {
            const float x = fmap(Kf[t + HD * k]);
            Kf[t + HD * k] = x;
            kp += x;
        }
        __syncthreads();

        // consume 32 rows: 3 b128 LDS reads per 32 FMA per thread
        #pragma unroll 4
        for (int s = 0; s < CHUNK; ++s) {
            const float4 ka = *reinterpret_cast<const float4*>(&Kt[s][hcol + d0]);
            const float4 kb = *reinterpret_cast<const float4*>(&Kt[s][hcol + d0 + 4]);
            const float4 vq = *reinterpret_cast<const float4*>(&Vt[s][hcol + v0]);
            const float kd[8] = {ka.x, ka.y, ka.z, ka.w, kb.x, kb.y, kb.z, kb.w};
            const float vs[4] = {vq.x, vq.y, vq.z, vq.w};
            #pragma unroll
            for (int a = 0; a < 8; ++a)
                #pragma unroll
                for (int b = 0; b < 4; ++b)
                    acc[a][b] += kd[a] * vs[b];
        }
        __syncthreads();   // before next round's DMA overwrites Kt/Vt
    }

    // ---- write partial: thread owns distinct (hg, d0..d0+7, v0..v0+3) ----
    float* P = part + ((size_t)c * NH + n * H_ + hg) * PART_STRIDE;
    #pragma unroll
    for (int a = 0; a < 8; ++a)
        *reinterpret_cast<float4*>(&P[(d0 + a) * D_ + v0]) =
            make_float4(acc[a][0], acc[a][1], acc[a][2], acc[a][3]);
    // Ksum: column t = head t>>5, dim t&31
    part[((size_t)c * NH + n * H_ + (t >> 5)) * PART_STRIDE + D_ * D_ + (t & 31)] = kp;
}

// ---------------- reduce the SPL partials ----------------------------------
template<int SPL>
__global__ __launch_bounds__(256) void lin_attn_reduce(
        const float* __restrict__ part, float* __restrict__ red) {
    const int i = blockIdx.x * 256 + threadIdx.x;
    if (i >= NH * PART_STRIDE) return;
    float s = 0.0f;
    #pragma unroll 8
    for (int sc = 0; sc < SPL; ++sc)
        s += part[(size_t)sc * (NH * PART_STRIDE) + i];
    red[i] = s;
}

// ---------------- phase 2: out = (Q'.KV) * zinv, zinv = 1/(Q'.Ksum+eps) ----
// (round-7/8 version verbatim — measured ~20us, near its 21us HBM floor)
__global__ __launch_bounds__(256) void lin_attn_phase2(
        const float* __restrict__ Qg, const float* __restrict__ red,
        float* __restrict__ outg) {
    constexpr int QTS = 32;           // Q tile rows
    constexpr int NLC = L_ / LCH;     // 32
    const int nh  = blockIdx.x / NLC;
    const int lcb = blockIdx.x % NLC;
    const int n = nh / H_, h = nh % H_;
    const int t = threadIdx.x;
    const int v  = t & 31;
    const int rb = t >> 5;            // 0..7
    const int r  = t >> 3;            // staging row 0..31
    const int c  = (t & 7) << 2;      // staging col

    __shared__ __align__(16) float Qt[QTS][D_];
    __shared__ float zinv_sh[QTS];

    // Pin this thread's KV column in registers (static indexing only).
    float kv[D_];
    const float* W = red + (size_t)nh * PART_STRIDE;
    #pragma unroll
    for (int d = 0; d < D_; ++d) kv[d] = W[d * D_ + v];
    // Ksum quad matching this thread's staging columns (runtime c -> load
    // from global, NOT a runtime-indexed register array).
    const float4 ksq = *reinterpret_cast<const float4*>(W + D_ * D_ + c);

    const size_t base = (size_t)n * L_ * H_ * D_ + (size_t)h * D_;
    const int l0 = lcb * LCH;
    for (int step = 0; step < LCH; step += QTS) {
        const float4 q4 = *reinterpret_cast<const float4*>(
            Qg + base + (size_t)(l0 + step + r) * (H_ * D_) + c);
        __syncthreads();   // previous Qt/zinv fully consumed
        float4 qf;
        qf.x = fmap(q4.x); qf.y = fmap(q4.y);
        qf.z = fmap(q4.z); qf.w = fmap(q4.w);
        *reinterpret_cast<float4*>(&Qt[r][c]) = qf;
        // per-row z: dot(q-quad, ksum-quad), folded across the 8 staging lanes
        float zp = qf.x * ksq.x + qf.y * ksq.y + qf.z * ksq.z + qf.w * ksq.w;
        zp += __shfl_xor(zp, 1);
        zp += __shfl_xor(zp, 2);
        zp += __shfl_xor(zp, 4);
        if ((t & 7) == 0) zinv_sh[r] = 1.0f / (zp + EPS_);
        __syncthreads();
        #pragma unroll
        for (int rr = 0; rr < 4; ++rr) {
            const int row = (rr << 3) + rb;
            float acc = 0.0f;
            #pragma unroll
            for (int d2 = 0; d2 < 16; ++d2) {   // b64 2-addr broadcast reads
                const float2 q = *reinterpret_cast<const float2*>(&Qt[row][d2 << 1]);
                acc += q.x * kv[(d2 << 1)] + q.y * kv[(d2 << 1) + 1];
            }
            outg[base + (size_t)(l0 + step + row) * (H_ * D_) + v] =
                acc * zinv_sh[row];
        }
    }
}

extern "C" void kernel_launch(void* const* d_in, const int* in_sizes, int n_in,
                              void* d_out, int out_size, void* d_ws, size_t ws_size,
                              hipStream_t stream) {
    const float* Q = (const float*)d_in[0];
    const float* K = (const float*)d_in[1];
    const float* V = (const float*)d_in[2];
    float* out  = (float*)d_out;
    float* part = (float*)d_ws;

    const size_t need64 = ((size_t)64 + 1) * NH * PART_STRIDE * sizeof(float);
    if (ws_size >= need64) {
        constexpr int SP = 64;   // 512 blocks = 2/CU, part 17.3MB (proven fit)
        float* red = part + (size_t)SP * NH * PART_STRIDE;
        lin_attn_phase1<SP><<<N_ * SP, 256, 0, stream>>>(K, V, part);
        lin_attn_reduce<SP><<<(NH * PART_STRIDE + 255) / 256, 256, 0, stream>>>(part, red);
        lin_attn_phase2<<<NH * (L_ / LCH), 256, 0, stream>>>(Q, red, out);
    } else {
        constexpr int SP = 16;   // fallback: 128 blocks, part 4.3MB
        float* red = part + (size_t)SP * NH * PART_STRIDE;
        lin_attn_phase1<SP><<<N_ * SP, 256, 0, stream>>>(K, V, part);
        lin_attn_reduce<SP><<<(NH * PART_STRIDE + 255) / 256, 256, 0, stream>>>(part, red);
        lin_attn_phase2<<<NH * (L_ / LCH), 256, 0, stream>>>(Q, red, out);
    }
}